// Round 1
// baseline (210.586 us; speedup 1.0000x reference)
//
#include <hip/hip_runtime.h>
#include <hip/hip_bf16.h>

#define IN_C  256
#define OUT_C 256
#define HH 56
#define WW 56
#define NN 32
#define XT_H 58
#define XT_W 64
#define WT_BYTES (8*9*256*32*2)  /* 1,179,648 B */

using short8 = __attribute__((ext_vector_type(8))) short;
using f32x4  = __attribute__((ext_vector_type(4))) float;

__device__ __forceinline__ void gload_lds16(const void* g, void* l) {
  __builtin_amdgcn_global_load_lds((const __attribute__((address_space(1))) void*)g,
                                   (__attribute__((address_space(3))) void*)l,
                                   16, 0, 0);
}

// weight fp32 OIHW -> wt bf16 [chunk(8)][tap(9)][oc(256)][ic5(32)]
__global__ void k_wconv(const float* __restrict__ w, __hip_bfloat16* __restrict__ wt) {
  int idx = blockIdx.x * 256 + threadIdx.x;
  if (idx >= OUT_C * IN_C * 9) return;
  int kw = idx % 3; int t1 = idx / 3;
  int kh = t1 % 3;  int t2 = t1 / 3;
  int ic = t2 % IN_C; int oc = t2 / IN_C;
  int tap = kh * 3 + kw;
  int chunk = ic >> 5, ic5 = ic & 31;
  wt[(((chunk * 9 + tap) * 256 + oc) * 32) + ic5] = __float2bfloat16(w[idx]);
}

// zero the halo cells of xt [n][58][64][256]
__global__ void k_xpad(__hip_bfloat16* __restrict__ xt) {
  int cell = blockIdx.x * 256 + threadIdx.x;
  if (cell >= NN * XT_H * XT_W) return;
  int wp = cell & 63; int t = cell >> 6;
  int hp = t % XT_H;
  if (hp == 0 || hp == 57 || wp == 0 || wp >= 57) {
    int4 z; z.x = 0; z.y = 0; z.z = 0; z.w = 0;
    int4* p = (int4*)(xt + (size_t)cell * 256);
#pragma unroll
    for (int i = 0; i < 32; ++i) p[i] = z;
  }
}

// x fp32 NCHW -> xt bf16 padded NHWC [n][hp=h+1][wp=w+1][ic]
__global__ void k_xconv(const float* __restrict__ x, __hip_bfloat16* __restrict__ xt) {
  __shared__ __hip_bfloat16 tile[64][58];
  int bid = blockIdx.x;
  int icb = bid & 3; int t = bid >> 2;
  int h = t % HH; int n = t / HH;
  for (int e = threadIdx.x; e < 64 * 56; e += 256) {
    int i = e / 56, w = e - i * 56;
    tile[i][w] = __float2bfloat16(x[(((size_t)n * IN_C + icb * 64 + i) * HH + h) * WW + w]);
  }
  __syncthreads();
  for (int e = threadIdx.x; e < 56 * 64; e += 256) {
    int w = e >> 6, i = e & 63;
    xt[((size_t)(n * XT_H + h + 1) * XT_W + (w + 1)) * 256 + icb * 64 + i] = tile[i][w];
  }
}

// main: implicit GEMM conv. block = (n, 4 output rows) = 224 pixels x 256 oc.
// 8 waves: wm = pixel half (112), wn = oc quarter (64).
__global__ __launch_bounds__(512, 2) void k_conv(
    const __hip_bfloat16* __restrict__ wt, const __hip_bfloat16* __restrict__ xt,
    const float* __restrict__ bias, float* __restrict__ out) {
  __shared__ __align__(16) short xs[6 * 64 * 32];   // [row6][col64][ic32] 24 KB
  __shared__ __align__(16) short wsm[256 * 32];     // [oc256][ic32]       16 KB

  const int tid  = threadIdx.x;
  const int wid  = tid >> 6, lane = tid & 63;
  const int c    = lane & 15, g = lane >> 4;
  const int wn   = wid & 3,  wm = wid >> 2;
  const int n    = blockIdx.x / 14, q = blockIdx.x % 14;
  const int h0   = q * 4;

  int xoff[7], rp_[7], wp_[7];
#pragma unroll
  for (int pt = 0; pt < 7; ++pt) {
    int p = wm * 112 + pt * 16 + c;
    int rp = p / 56, wp = p - rp * 56;
    rp_[pt] = rp; wp_[pt] = wp;
    xoff[pt] = rp * 4096 + wp * 64 + g * 16;   // byte offset in xs (row*64cols*64B + col*64B + g*16B)
  }
  const int woffb = (wn * 64 + c) * 64 + g * 16;

  f32x4 acc[4][7];
#pragma unroll
  for (int a = 0; a < 4; ++a)
#pragma unroll
    for (int b = 0; b < 7; ++b) acc[a][b] = (f32x4){0.f, 0.f, 0.f, 0.f};

  const __hip_bfloat16* xtn = xt + (size_t)(n * XT_H + h0) * XT_W * 256;
  char* xs_c = (char*)xs;
  char* ws_c = (char*)wsm;

  for (int chunk = 0; chunk < 8; ++chunk) {
    // stage x chunk: 6 rows x 64 cols x 32 ic bf16 = 24 strips of 1 KiB; 3 per wave
#pragma unroll
    for (int i = 0; i < 3; ++i) {
      int s = wid * 3 + i;
      int row = s >> 2, colq = s & 3;
      const __hip_bfloat16* src = xtn + (size_t)(row * 64 + colq * 16 + (lane >> 2)) * 256
                                      + chunk * 32 + (lane & 3) * 8;
      gload_lds16(src, xs_c + row * 4096 + colq * 1024);
    }
#pragma unroll
    for (int tap = 0; tap < 9; ++tap) {
      const int kh = tap / 3, kw = tap % 3;
      // stage weights for (chunk, tap): 16 KiB = 16 strips; 2 per wave
#pragma unroll
      for (int i = 0; i < 2; ++i) {
        int s = wid * 2 + i;
        const __hip_bfloat16* src = wt + (size_t)((chunk * 9 + tap) * 256 + s * 16 + (lane >> 2)) * 32
                                       + (lane & 3) * 8;
        gload_lds16(src, ws_c + s * 1024);
      }
      __syncthreads();   // compiler drains vmcnt/lgkmcnt before barrier

      short8 xf[7], wf[4];
#pragma unroll
      for (int pt = 0; pt < 7; ++pt)
        xf[pt] = *(const short8*)(xs_c + (xoff[pt] + kh * 4096 + kw * 64));
#pragma unroll
      for (int oct = 0; oct < 4; ++oct)
        wf[oct] = *(const short8*)(ws_c + (woffb + oct * 1024));
#pragma unroll
      for (int oct = 0; oct < 4; ++oct)
#pragma unroll
        for (int pt = 0; pt < 7; ++pt)
          acc[oct][pt] = __builtin_amdgcn_mfma_f32_16x16x32_bf16(wf[oct], xf[pt], acc[oct][pt], 0, 0, 0);
      __syncthreads();   // protect wsm (and xs at chunk boundary) overwrite
    }
  }

  // epilogue: D row(4g+r)=oc offset, D col(c)=pixel offset -> coalesced stores over c
#pragma unroll
  for (int oct = 0; oct < 4; ++oct) {
    const int oc0 = wn * 64 + oct * 16 + 4 * g;
#pragma unroll
    for (int r = 0; r < 4; ++r) {
      const float bv = bias[oc0 + r];
      const size_t obase = ((size_t)n * OUT_C + (oc0 + r)) * (HH * WW);
#pragma unroll
      for (int pt = 0; pt < 7; ++pt)
        out[obase + (size_t)(h0 + rp_[pt]) * 56 + wp_[pt]] = acc[oct][pt][r] + bv;
    }
  }
}

extern "C" void kernel_launch(void* const* d_in, const int* in_sizes, int n_in,
                              void* d_out, int out_size, void* d_ws, size_t ws_size,
                              hipStream_t stream) {
  const float* x    = (const float*)d_in[0];
  const float* w    = (const float*)d_in[1];
  const float* bias = (const float*)d_in[2];
  float* out        = (float*)d_out;

  __hip_bfloat16* wt = (__hip_bfloat16*)d_ws;
  __hip_bfloat16* xt = (__hip_bfloat16*)((char*)d_ws + WT_BYTES);

  k_wconv<<<(OUT_C * IN_C * 9 + 255) / 256, 256, 0, stream>>>(w, wt);
  k_xpad <<<(NN * XT_H * XT_W + 255) / 256, 256, 0, stream>>>(xt);
  k_xconv<<<NN * HH * 4, 256, 0, stream>>>(x, xt);
  k_conv <<<NN * 14, 512, 0, stream>>>(wt, xt, bias, out);
}